// Round 7
// baseline (483.803 us; speedup 1.0000x reference)
//
#include <hip/hip_runtime.h>

// WaveCell: single persistent cooperative kernel, 16 chunks x 16 steps,
// POINT-TO-POINT neighbor sync between chunks (no grid.sync, no relaunch).
// Each block owns a 24x24 tile on a 56x56 extended LDS region (round-6
// inner loop verbatim). Between chunks: release own flag at agent scope,
// spin on <=8 clamped neighbor flags (relaxed agent loads), acquire fence,
// then reload only halo patches' y(t-1)/y(t-2) from `out`.
// Flags live in d_ws: poison 0xAAAAAAAA is negative as signed int and polls
// check >= chunk >= 1, so no initialization is needed (deadlock-free).

#define NXg 192
#define NYg 192
#define BATCH 4
#define TSTEPS 256
#define CELLS (NXg * NYg)

#define TS 24                   // output tile side
#define KSTEP 16                // time steps per chunk
#define NCHUNK (TSTEPS / KSTEP) // 16
#define EXT 56                  // TS + 2*KSTEP
#define LROWS (EXT + 2)         // guard row top + bottom
#define LPITCH 68               // dwords/row: 4 pad | 56 data | 8 pad
#define LSZ (LROWS * LPITCH)
#define NTHREADS 448            // 56 rows x 8 lanes/row = 7 waves

#define SRC_X 96
#define SRC_Y 32
#define FLAG_STRIDE 32          // ints per flag (128 B line)

__global__ __launch_bounds__(NTHREADS) void wave_persist_kernel(
    const float* __restrict__ cgp, const float* __restrict__ bgp,
    const float* __restrict__ x, float* __restrict__ out,
    int* __restrict__ flags) {
  __shared__ float buf0[LSZ];
  __shared__ float buf1[LSZ];
  __shared__ float xsh[TSTEPS];

  const int tid = threadIdx.x;
  const int lr = tid >> 3;      // local row 0..55
  const int lg = tid & 7;       // 8-wide group; lg==7 is the zero lane
  const int bcol = blockIdx.x;  // 0..7
  const int brow = blockIdx.y;  // 0..7
  const int bb = blockIdx.z;    // 0..3
  const int r0 = brow * TS - KSTEP;
  const int c0 = bcol * TS - KSTEP;
  const int obase = bb * TSTEPS * CELLS;
  const float inv_h2 = (float)(1.0 / (2.0 * 1.01 * 1.01 * 1.0e-3 * 1.0e-3));

  const int gr = r0 + lr;
  const int gc = c0 + 8 * lg;
  const bool id = (lg < 7) && (gr >= 0) && (gr < NXg) && (gc >= 0) && (gc < NYg);
  const bool til = (lr >= KSTEP) && (lr < KSTEP + TS) && (lg >= 2) && (lg < 5);
  const bool ref = id && !til;  // halo patch: reload at chunk boundaries
  const int gofs = id ? (gr * NYg + gc) : 0;

  // Sync bookkeeping.
  int* myflag = flags + (((bb << 6) + (brow << 3) + bcol) * FLAG_STRIDE);
  int* nbrflag = myflag;
  if (tid < 8) {
    const int nidx = tid < 4 ? tid : tid + 1;  // skip (0,0)
    int rr = brow + nidx / 3 - 1;
    int cc = bcol + nidx % 3 - 1;
    rr = rr < 0 ? 0 : (rr > 7 ? 7 : rr);
    cc = cc < 0 ? 0 : (cc > 7 ? 7 : cc);
    nbrflag = flags + (((bb << 6) + (rr << 3) + cc) * FLAG_STRIDE);
  }

  const float4 z4 = make_float4(0.f, 0.f, 0.f, 0.f);

  // ---- Prologue (once). ----
  float4 cv0 = z4, cv1 = z4, bv0 = z4, bv1 = z4;
  if (id) {
    cv0 = *(const float4*)(cgp + gofs);
    cv1 = *(const float4*)(cgp + gofs + 4);
    bv0 = *(const float4*)(bgp + gofs);
    bv1 = *(const float4*)(bgp + gofs + 4);
  }
  // x -> LDS (64 float4 = 256 samples of this batch).
  if (tid < 64) {
    ((float4*)xsh)[tid] = ((const float4*)(x + bb * TSTEPS))[tid];
  }
  // Zero guard rows (0 and LROWS-1), dwords 4..67, both buffers.
  if (tid >= 64 && tid < 128) {
    const int t2 = tid - 64;
    const int sel = t2 >> 4;
    const int g = t2 & 15;
    float* base = (sel & 2) ? buf1 : buf0;
    const int row = (sel & 1) ? (LROWS - 1) : 0;
    *(float4*)&base[row * LPITCH + 4 + 4 * g] = z4;
  }

  float4 ai0 = z4, ai1 = z4, cf0 = z4, cf1 = z4, cs0 = z4, cs1 = z4;
  float4 sm0 = z4, sm1 = z4;
  if (id) {
    ai0.x = 1.0f / (1.0e6f + 500.0f * bv0.x);
    ai0.y = 1.0f / (1.0e6f + 500.0f * bv0.y);
    ai0.z = 1.0f / (1.0e6f + 500.0f * bv0.z);
    ai0.w = 1.0f / (1.0e6f + 500.0f * bv0.w);
    ai1.x = 1.0f / (1.0e6f + 500.0f * bv1.x);
    ai1.y = 1.0f / (1.0e6f + 500.0f * bv1.y);
    ai1.z = 1.0f / (1.0e6f + 500.0f * bv1.z);
    ai1.w = 1.0f / (1.0e6f + 500.0f * bv1.w);
    cf0.x = 1.0e6f - 500.0f * bv0.x;
    cf0.y = 1.0e6f - 500.0f * bv0.y;
    cf0.z = 1.0e6f - 500.0f * bv0.z;
    cf0.w = 1.0e6f - 500.0f * bv0.w;
    cf1.x = 1.0e6f - 500.0f * bv1.x;
    cf1.y = 1.0e6f - 500.0f * bv1.y;
    cf1.z = 1.0e6f - 500.0f * bv1.z;
    cf1.w = 1.0e6f - 500.0f * bv1.w;
    cs0.x = cv0.x * cv0.x; cs0.y = cv0.y * cv0.y;
    cs0.z = cv0.z * cv0.z; cs0.w = cv0.w * cv0.w;
    cs1.x = cv1.x * cv1.x; cs1.y = cv1.y * cv1.y;
    cs1.z = cv1.z * cv1.z; cs1.w = cv1.w * cv1.w;
    if (gr == SRC_X) {
      sm0.x = (gc + 0 == SRC_Y) ? 1.0f : 0.0f;
      sm0.y = (gc + 1 == SRC_Y) ? 1.0f : 0.0f;
      sm0.z = (gc + 2 == SRC_Y) ? 1.0f : 0.0f;
      sm0.w = (gc + 3 == SRC_Y) ? 1.0f : 0.0f;
      sm1.x = (gc + 4 == SRC_Y) ? 1.0f : 0.0f;
      sm1.y = (gc + 5 == SRC_Y) ? 1.0f : 0.0f;
      sm1.z = (gc + 6 == SRC_Y) ? 1.0f : 0.0f;
      sm1.w = (gc + 7 == SRC_Y) ? 1.0f : 0.0f;
    }
  }

  // Field state: chunk 0 starts from zeros.
  float4 yc0 = z4, yc1 = z4, yp0 = z4, yp1 = z4;

  const int lo = (lr + 1) * LPITCH + 4 + 8 * lg;
  // Scatter y(-1)=0 into buf0 (also zeroes buf0's data region).
  *(float4*)&buf0[lo] = yc0;
  *(float4*)&buf0[lo + 4] = yc1;
  __syncthreads();

  float* ping = buf0;
  float* pong = buf1;

  for (int chunk = 0; chunk < NCHUNK; ++chunk) {
    const int t0 = chunk * KSTEP;

    if (chunk > 0) {
      // __syncthreads at end of previous chunk's loop + the post-loop store
      // below means: drain own stores, then release flag, then wait.
      __syncthreads();  // every wave: vmcnt(0) before s_barrier
      if (tid == 0) {
        __hip_atomic_store(myflag, chunk, __ATOMIC_RELEASE,
                           __HIP_MEMORY_SCOPE_AGENT);
      }
      if (tid < 8) {
        while (__hip_atomic_load(nbrflag, __ATOMIC_RELAXED,
                                 __HIP_MEMORY_SCOPE_AGENT) < chunk) {
          __builtin_amdgcn_s_sleep(2);
        }
        __builtin_amdgcn_fence(__ATOMIC_ACQUIRE, "agent");
      }
      __syncthreads();

      // Reload halo patches' y(t-1), y(t-2); interior register state and
      // ping(==buf0) interior cells are valid from the previous chunk.
      if (ref) {
        yc0 = *(const float4*)(out + obase + (t0 - 1) * CELLS + gofs);
        yc1 = *(const float4*)(out + obase + (t0 - 1) * CELLS + gofs + 4);
        yp0 = *(const float4*)(out + obase + (t0 - 2) * CELLS + gofs);
        yp1 = *(const float4*)(out + obase + (t0 - 2) * CELLS + gofs + 4);
        *(float4*)&ping[lo] = yc0;
        *(float4*)&ping[lo + 4] = yc1;
      }
      __syncthreads();
    }

    float4 pv0 = z4, pv1 = z4;
    float* pop = out;

#pragma unroll
    for (int j = 0; j < KSTEP; ++j) {
      const float xt = xsh[t0 + j];
      float* op = out + obase + (t0 + j) * CELLS;

      if (j > 0 && til) {  // pipelined store of previous step's output
        *(float4*)(pop + gofs) = pv0;
        *(float4*)(pop + gofs + 4) = pv1;
      }

      float lqw = __shfl_up(yc1.w, 1);
      lqw = (lg == 0) ? 0.0f : lqw;
      float rqx = __shfl_down(yc0.x, 1);

      float4 up0 = *(float4*)&ping[lo - LPITCH];
      float4 up1 = *(float4*)&ping[lo - LPITCH + 4];
      float4 dn0 = *(float4*)&ping[lo + LPITCH];
      float4 dn1 = *(float4*)&ping[lo + LPITCH + 4];

      float4 val0, val1;
      {
        float lap = inv_h2 * (up0.x + dn0.x + lqw + yc0.y - 4.0f * yc0.x);
        val0.x = ai0.x * (2.0e6f * yc0.x - cf0.x * yp0.x + cs0.x * lap) + sm0.x * xt;
      }
      {
        float lap = inv_h2 * (up0.y + dn0.y + yc0.x + yc0.z - 4.0f * yc0.y);
        val0.y = ai0.y * (2.0e6f * yc0.y - cf0.y * yp0.y + cs0.y * lap) + sm0.y * xt;
      }
      {
        float lap = inv_h2 * (up0.z + dn0.z + yc0.y + yc0.w - 4.0f * yc0.z);
        val0.z = ai0.z * (2.0e6f * yc0.z - cf0.z * yp0.z + cs0.z * lap) + sm0.z * xt;
      }
      {
        float lap = inv_h2 * (up0.w + dn0.w + yc0.z + yc1.x - 4.0f * yc0.w);
        val0.w = ai0.w * (2.0e6f * yc0.w - cf0.w * yp0.w + cs0.w * lap) + sm0.w * xt;
      }
      {
        float lap = inv_h2 * (up1.x + dn1.x + yc0.w + yc1.y - 4.0f * yc1.x);
        val1.x = ai1.x * (2.0e6f * yc1.x - cf1.x * yp1.x + cs1.x * lap) + sm1.x * xt;
      }
      {
        float lap = inv_h2 * (up1.y + dn1.y + yc1.x + yc1.z - 4.0f * yc1.y);
        val1.y = ai1.y * (2.0e6f * yc1.y - cf1.y * yp1.y + cs1.y * lap) + sm1.y * xt;
      }
      {
        float lap = inv_h2 * (up1.z + dn1.z + yc1.y + yc1.w - 4.0f * yc1.z);
        val1.z = ai1.z * (2.0e6f * yc1.z - cf1.z * yp1.z + cs1.z * lap) + sm1.z * xt;
      }
      {
        float lap = inv_h2 * (up1.w + dn1.w + yc1.z + rqx - 4.0f * yc1.w);
        val1.w = ai1.w * (2.0e6f * yc1.w - cf1.w * yp1.w + cs1.w * lap) + sm1.w * xt;
      }

      yp0 = yc0; yp1 = yc1;
      yc0 = val0; yc1 = val1;

      *(float4*)&pong[lo] = val0;
      *(float4*)&pong[lo + 4] = val1;

      pv0 = val0; pv1 = val1; pop = op;

      __syncthreads();
      float* tmp = ping; ping = pong; pong = tmp;
    }

    // Final step's store (before the boundary barrier of the next chunk).
    if (til) {
      *(float4*)(pop + gofs) = pv0;
      *(float4*)(pop + gofs + 4) = pv1;
    }
  }
}

extern "C" void kernel_launch(void* const* d_in, const int* in_sizes, int n_in,
                              void* d_out, int out_size, void* d_ws,
                              size_t ws_size, hipStream_t stream) {
  const float* x = (const float*)d_in[0];  // [B, T, 1]
  const float* c = (const float*)d_in[1];  // [192,192]
  const float* b = (const float*)d_in[2];  // [192,192]
  float* out = (float*)d_out;              // [B, T, 192, 192]
  int* flags = (int*)d_ws;                 // 256 flags x 128 B = 32 KB

  void* args[] = {(void*)&c, (void*)&b, (void*)&x, (void*)&out, (void*)&flags};
  dim3 grid(NXg / TS, NYg / TS, BATCH);  // 8 x 8 x 4 = 256 blocks
  dim3 block(NTHREADS, 1, 1);
  (void)hipLaunchCooperativeKernel((const void*)wave_persist_kernel, grid,
                                   block, args, 0, stream);
}